// Round 2
// baseline (679.117 us; speedup 1.0000x reference)
//
#include <hip/hip_runtime.h>

// Problem constants
#define HH 2048
#define WW 2048
#define WSK 4095            // real skewed columns
#define WSKP 4096           // padded (col 4095 = dump column; fc reads 0..4094)
#define BLKS 8              // pipelined blocks (CUs)
#define NW  4               // waves per block
#define NT  (NW * 64)       // 256 threads, 1 row/thread
#define KCH 64              // R8: 32->64. Columns per chunk; amortizes the
                            // ~5K-cyc fixed per-epoch cost over 2x columns.
#define NCH (WSKP / KCH)    // 64 chunks
#define FC_IN 1024
#define FC_OUT 10
#define NFLAT ((HH * WW) / FC_IN)

// Inter-block mailbox: ring of {tag,value} u64 per block boundary, in d_out.
// 8 rings x 2048 slots x 8B = 128 KB <= 160 KB out buffer; fc_kernel later
// overwrites EVERY d_out element, so validation is unaffected. Tag = col+1;
// poison 0xAA.., memset 0, and fc's float outputs never alias tags <= 4096.
// R8 protocol (post-mortem of R7's +83us regression):
//   producer: RELAXED agent atomic store per column (write-through to the
//             coherent point; no release fence -> no vmcnt(0) drain, no L2
//             writeback on wave3's critical path).
//   consumer: ACQUIRE polling (per-iteration buffer_inv = prompt cross-XCD
//             visibility; R7's RELAXED polling span on stale local L2 until
//             eviction -- that was the regression).
#define MRING 2048

// tanh(x) = 1 - 2/(exp2(x*2/ln2)+1); caller passes pre-scaled xs = x*2/ln2.
__device__ __forceinline__ float tanh_pre(float xs) {
  float e = __builtin_amdgcn_exp2f(xs);
  float r = __builtin_amdgcn_rcpf(e + 1.0f);
  return __builtin_fmaf(-2.0f, r, 1.0f);
}

// Full-wave shift-up-by-1 via DPP wave_shr:1 (verified R5: exact absmax).
// result[l] = src[l-1], result[0] = old.
__device__ __forceinline__ float wave_shr1(float src, float old) {
  int r = __builtin_amdgcn_update_dpp(
      __builtin_bit_cast(int, old), __builtin_bit_cast(int, src),
      0x138 /*wave_shr:1*/, 0xF, 0xF, false);
  return __builtin_bit_cast(float, r);
}

// inp[c*HH+r] = S*(w*img[r][c-r] + b_in + b_state), bias-only off-image.
__global__ __launch_bounds__(256) void skew_kernel(
    const float* __restrict__ img, const float* __restrict__ w_in,
    const float* __restrict__ b_in, const float* __restrict__ b_state,
    float* __restrict__ inp) {
  const float S = 2.88539008177792681472f;   // 2/ln(2)
  const float ws = w_in[0] * S;
  const float Cs = (b_in[0] + b_state[0]) * S;
  int gid = blockIdx.x * 256 + threadIdx.x;  // gid = c*HH + r
  int r = gid & (HH - 1);
  int c = gid >> 11;
  int idx = c - r;
  float v = Cs;
  if ((unsigned)idx < (unsigned)WW) v = fmaf(ws, img[(size_t)r * WW + idx], Cs);
  inp[gid] = v;
}

// 8-block x 4-wave wavefront-pipelined scan, 1 row/thread.
// R8 vs R6 (438 us): KCH=64 (epoch-overhead amortization) + mailbox handoff
// with acquire-polled, prefetch-validated boundary (removes wave0's exposed
// ~900cy cross-XCD gather and wave3's release-fence L2 writeback per epoch).
// Ring semantics (verified R2-R5): ring[e&1][w][i] = wave w's h AFTER column
// c0+i-1; slot 0 at chunk start, slot i+1 after column i.
// inp/acts are the same buffer; within a wave, loads touch chunk ch+1 and
// stores chunk ch (disjoint) except the never-consumed clamped reload at the
// final chunk -> restrict is operationally safe.
__global__ __launch_bounds__(NT) void scan_kernel(
    const float* __restrict__ w_state, const float* __restrict__ inp,
    float* __restrict__ acts, unsigned long long* __restrict__ mbox) {
  const int t = threadIdx.x;
  const int wv = t >> 6;
  const int lane = t & 63;
  const int blk = blockIdx.x;
  const int r = blk * NT + t;                // global row (1 per thread)

  const float S = 2.88539008177792681472f;
  const float k0s = w_state[0] * S;
  const float k1s = w_state[1] * S;

  __shared__ float ring[2][NW][KCH];

  float h = 0.0f;
  const float* colp_in = inp + r;
  float* colp_out = acts + r;

  // Prime prefetch registers with chunk 0 (whole chunk).
  float pf[KCH];
  #pragma unroll
  for (int d = 0; d < KCH; ++d) pf[d] = colp_in[(size_t)d * HH];

  // Prime + validate chunk 0's boundary (wave 0, blk>0): acquire-poll until
  // every lane's tag matches, so the in-loop use is wait-free.
  unsigned long long praw = 0;
  if (wv == 0 && blk > 0) {
    unsigned long long* mb_up = mbox + (size_t)(blk - 1) * MRING;
    const int cl = lane - 1;
    const bool need = (cl >= 0);
    const unsigned want = (unsigned)(cl + 1);
    if (need)
      praw = __hip_atomic_load(&mb_up[cl & (MRING - 1)], __ATOMIC_ACQUIRE,
                               __HIP_MEMORY_SCOPE_AGENT);
    while (!__all((!need) || ((unsigned)(praw >> 32) == want))) {
      __builtin_amdgcn_s_sleep(1);
      if (need)
        praw = __hip_atomic_load(&mb_up[cl & (MRING - 1)], __ATOMIC_ACQUIRE,
                                 __HIP_MEMORY_SCOPE_AGENT);
    }
  }

  for (int e = 0; e < NCH + NW - 1; ++e) {
    const int ch = e - wv;
    if (0 <= ch && ch < NCH) {
      const int c0 = ch * KCH;

      // Boundary values for this chunk, lanes 0..63:
      // lane i = neighbor-row h AFTER column c0+i-1.
      float bvec;
      if (wv == 0) {
        bvec = 0.0f;
        if (blk > 0) {
          // praw was validated (tags matched) before this epoch.
          const int cl = c0 + lane - 1;
          if (cl >= 0) bvec = __builtin_bit_cast(float, (unsigned)praw);
        }
      } else {
        // Written entirely by wave wv-1 during the previous epoch.
        bvec = ring[(e & 1) ^ 1][wv - 1][lane];
      }
      if (lane == 63 && wv != NW - 1) ring[e & 1][wv][0] = h;

      // Back-pressure before reusing wrapped mailbox slots (never spins in
      // practice: downstream lags ~4 epochs = ~256 cols << 1920-col margin;
      // relaxed is safe here -- stale reads self-resolve via L2 eviction
      // under the streaming pf traffic, and this path never triggers).
      if (wv == NW - 1 && blk + 1 < BLKS) {
        const int cmax = c0 + KCH - 1;
        if (cmax >= MRING) {
          unsigned long long* mb_dn = mbox + (size_t)(blk + 1) * MRING;
          const int cref = cmax - (MRING - 128);
          const unsigned wantt = (unsigned)(cref + 1);
          if (lane == 63) {
            while ((unsigned)(__hip_atomic_load(&mb_dn[cref & (MRING - 1)],
                       __ATOMIC_RELAXED, __HIP_MEMORY_SCOPE_AGENT) >> 32)
                   != wantt)
              __builtin_amdgcn_s_sleep(8);
          }
        }
      }

      // Next-chunk prefetch base (clamped reload at final chunk, unused).
      const int cb = (ch + 1 < NCH ? ch + 1 : ch) * KCH;
      unsigned long long* mb_my = mbox + (size_t)blk * MRING;

      #pragma unroll
      for (int cc = 0; cc < KCH; ++cc) {
        float cur = pf[cc];
        pf[cc] = colp_in[(size_t)(cb + cc) * HH];

        // Boundary value for lane 0, off the critical chain (SALU readlane).
        float pv = __builtin_bit_cast(float,
            __builtin_amdgcn_readlane(__builtin_bit_cast(int, bvec), cc));
        float prev = wave_shr1(h, pv);   // prev[l]=h[l-1], prev[0]=pv

        h = tanh_pre(fmaf(k0s, prev, fmaf(k1s, h, cur)));

        if (lane == 63) {
          if (wv != NW - 1) {
            if (cc + 1 < KCH) ring[e & 1][wv][cc + 1] = h;
          } else {
            // Publish {tag,value}: single relaxed agent atomic store
            // (write-through to the coherent point; self-validating).
            unsigned long long pack =
                ((unsigned long long)(unsigned)(c0 + cc + 1) << 32) |
                (unsigned long long)__builtin_bit_cast(unsigned, h);
            __hip_atomic_store(&mb_my[(c0 + cc) & (MRING - 1)], pack,
                               __ATOMIC_RELAXED, __HIP_MEMORY_SCOPE_AGENT);
          }
        }
        colp_out[(size_t)(c0 + cc) * HH] = h;   // unconditional (4095 = dump)
      }

      // Prefetch + validate NEXT chunk's boundary at epoch end: upstream
      // publishes it just-in-time (steady stagger = NW epochs), so the spin
      // is ~0 and the load latency hides under the barrier.
      if (wv == 0 && blk > 0 && ch + 1 < NCH) {
        unsigned long long* mb_up = mbox + (size_t)(blk - 1) * MRING;
        const int cl2 = (ch + 1) * KCH + lane - 1;   // >= 63: all lanes need
        const unsigned want = (unsigned)(cl2 + 1);
        praw = __hip_atomic_load(&mb_up[cl2 & (MRING - 1)], __ATOMIC_ACQUIRE,
                                 __HIP_MEMORY_SCOPE_AGENT);
        while (!__all((unsigned)(praw >> 32) == want)) {
          __builtin_amdgcn_s_sleep(1);
          praw = __hip_atomic_load(&mb_up[cl2 & (MRING - 1)],
                                   __ATOMIC_ACQUIRE,
                                   __HIP_MEMORY_SCOPE_AGENT);
        }
      }
    }
    // LDS-only barrier: rotates the ring double-buffer WITHOUT draining
    // vmcnt, so next-chunk prefetches survive the epoch boundary.
    asm volatile("s_waitcnt lgkmcnt(0)\n\ts_barrier" ::: "memory");
  }
}

// Unskew + FC, coalesced: one block per 16 acts-rows (32 flat rows).
// acts[col][r0..r0+15] tiles are loaded as 64B row-segments (every fetched
// line fully used), transposed through LDS, and dotted against LDS-staged
// fc_w. flat[i][k] = acts[(i>>1)+(i&1)*1024+k][i>>1].
#define FCR 16                 // acts rows per block
#define FCCH 256               // column chunk staged in LDS
#define FCT 256                // threads per block

__global__ __launch_bounds__(FCT) void fc_kernel(
    const float* __restrict__ acts, const float* __restrict__ fc_w,
    const float* __restrict__ fc_b, float* __restrict__ out) {
  __shared__ float fcw[FC_OUT * FC_IN];        // 40 KB
  __shared__ float tile[FCCH][FCR + 1];        // 17.4 KB, +1 pad vs banks

  const int tid = threadIdx.x;
  const int bb = blockIdx.x;
  const int r0 = bb * FCR;

  for (int i = tid; i < FC_OUT * FC_IN; i += FCT) fcw[i] = fc_w[i];

  const int il = tid >> 3;                 // flat-row local index 0..31
  const int cs = tid & 7;                  // column slice 0..7
  const int rloc = il >> 1;                // local acts row 0..15
  const int koff = (r0 + rloc) + ((il & 1) << 10);   // k = col - koff

  const int lrr = tid & 15;                // staging: row
  const int lco = tid >> 4;                // staging: col 0..15

  float acc[FC_OUT];
  #pragma unroll
  for (int j = 0; j < FC_OUT; ++j) acc[j] = 0.0f;

  __syncthreads();

  const int cend = r0 + FCR - 1 + 2047;    // last needed col = r0 + 2062
  for (int cb = r0; cb <= cend; cb += FCCH) {
    // Stage tile[cc][rr] = acts[(cb+cc)*HH + r0+rr]; 16 consecutive floats
    // per col -> 64B coalesced segments.
    #pragma unroll
    for (int s = 0; s < FCCH / 16; ++s) {
      int cc = s * 16 + lco;
      int col = cb + cc;
      int colc = col < WSK ? col : (WSK - 1);  // clamp; k-guard protects use
      tile[cc][lrr] = acts[(size_t)colc * HH + r0 + lrr];
    }
    __syncthreads();

    // Each thread: its flat row, cols == cs (mod 8) of this chunk.
    #pragma unroll 4
    for (int tt = 0; tt < FCCH / 8; ++tt) {
      int cc = tt * 8 + cs;
      int k = cb + cc - koff;
      if (0 <= k && k < FC_IN) {
        float v = tile[cc][rloc];
        #pragma unroll
        for (int j = 0; j < FC_OUT; ++j)
          acc[j] = fmaf(v, fcw[j * FC_IN + k], acc[j]);
      }
    }
    __syncthreads();
  }

  // Reduce the 8 column-slice partials (8 consecutive lanes, wave-aligned).
  #pragma unroll
  for (int j = 0; j < FC_OUT; ++j) {
    acc[j] += __shfl_down(acc[j], 4, 8);
    acc[j] += __shfl_down(acc[j], 2, 8);
    acc[j] += __shfl_down(acc[j], 1, 8);
  }
  if (cs == 0) {
    const int i = bb * 32 + il;              // flat row
    #pragma unroll
    for (int j = 0; j < FC_OUT; ++j) out[i * FC_OUT + j] = acc[j] + fc_b[j];
  }
}

extern "C" void kernel_launch(void* const* d_in, const int* in_sizes, int n_in,
                              void* d_out, int out_size, void* d_ws, size_t ws_size,
                              hipStream_t stream) {
  const float* x       = (const float*)d_in[0];
  const float* w_in    = (const float*)d_in[1];
  const float* b_in    = (const float*)d_in[2];
  const float* w_state = (const float*)d_in[3];
  const float* b_state = (const float*)d_in[4];
  const float* fc_w    = (const float*)d_in[5];
  const float* fc_b    = (const float*)d_in[6];
  float* out = (float*)d_out;
  float* buf = (float*)d_ws;   // WSKP*HH*4 = 32 MiB: inp -> acts in-place

  // Mailboxes live in d_out (128 KB of its 160 KB): scan writes {tag,value}
  // words there; fc_kernel later overwrites EVERY d_out element with real
  // outputs, so validation is unaffected. Poison/memset/fc-float bit patterns
  // never equal an expected tag, so rings are correctly "reset" every launch.
  // (Must be d_out, not d_ws: d_ws is NOT re-poisoned between launches and
  // leftover tags would falsely satisfy the waits.)
  unsigned long long* mbox = (unsigned long long*)d_out;

  skew_kernel<<<(WSKP * HH) / 256, 256, 0, stream>>>(x, w_in, b_in, b_state, buf);
  scan_kernel<<<BLKS, NT, 0, stream>>>(w_state, buf, buf, mbox);
  fc_kernel<<<HH / FCR, FCT, 0, stream>>>(buf, fc_w, fc_b, out);
}

// Round 3
// 575.559 us; speedup vs baseline: 1.1799x; 1.1799x over previous
//
#include <hip/hip_runtime.h>

// Problem constants
#define HH 2048
#define WW 2048
#define WSK 4095            // real skewed columns
#define WSKP 4096           // padded row stride (col 4095 = dump column)
#define BLKS 8              // pipelined blocks (CUs)
#define NW  4               // waves per block
#define NT  (NW * 64)       // 256 threads, 1 row/thread
#define KCH 32              // columns per chunk
#define NCH (WSKP / KCH)    // 128 chunks
#define FC_IN 1024
#define FC_OUT 10

// R9 layout flip: inp/acts are ROW-MAJOR [row][WSKP] (16KB stride).
// Rationale (R6-R8 post-mortem): per-column cost is ~207cyc regardless of
// epoch structure -> the stall lives in the column loop's per-column VMEM
// (2 ops/col, 64 outstanding/epoch = exactly the vmcnt(63) encoding cliff;
// R7/R8's extra per-column store fell off that cliff and regressed).
// Row-major makes each lane's chunk 128B contiguous: 8 dwordx4 loads +
// 8 dwordx4 stores per EPOCH (immediate-offset addressing), ZERO VMEM in
// the column loop. Also: boundary gather = 1 contiguous 32-float read
// (was 32x8KB-stride), ring writes batch to 8 LDS quads, and fc's unskew
// read becomes contiguous in k.

// tanh(x) = 1 - 2/(exp2(x*2/ln2)+1); caller passes pre-scaled xs = x*2/ln2.
__device__ __forceinline__ float tanh_pre(float xs) {
  float e = __builtin_amdgcn_exp2f(xs);
  float r = __builtin_amdgcn_rcpf(e + 1.0f);
  return __builtin_fmaf(-2.0f, r, 1.0f);
}

// Full-wave shift-up-by-1 via DPP wave_shr:1 (verified R5: exact absmax).
// result[l] = src[l-1], result[0] = old.
__device__ __forceinline__ float wave_shr1(float src, float old) {
  int r = __builtin_amdgcn_update_dpp(
      __builtin_bit_cast(int, old), __builtin_bit_cast(int, src),
      0x138 /*wave_shr:1*/, 0xF, 0xF, false);
  return __builtin_bit_cast(float, r);
}

// pf is float4[8]; extract element cc (compile-time constant) without
// going through memory (rule: runtime-indexed arrays -> scratch).
#define PFE(cc) ((cc & 3) == 0 ? pf[cc >> 2].x : \
                 (cc & 3) == 1 ? pf[cc >> 2].y : \
                 (cc & 3) == 2 ? pf[cc >> 2].z : pf[cc >> 2].w)

// inp_rm[r*WSKP + c] = S*(w*img[r][c-r] + b_in + b_state), bias-only
// off-image. Row-major: consecutive lanes = consecutive c -> coalesced
// reads AND writes (the old column-major version had strided img reads).
__global__ __launch_bounds__(256) void skew_kernel(
    const float* __restrict__ img, const float* __restrict__ w_in,
    const float* __restrict__ b_in, const float* __restrict__ b_state,
    float* __restrict__ inp) {
  const float S = 2.88539008177792681472f;   // 2/ln(2)
  const float ws = w_in[0] * S;
  const float Cs = (b_in[0] + b_state[0]) * S;
  int gid = blockIdx.x * 256 + threadIdx.x;  // gid = r*WSKP + c
  int c = gid & (WSKP - 1);
  int r = gid >> 12;
  int idx = c - r;
  float v = Cs;
  if ((unsigned)idx < (unsigned)WW) v = fmaf(ws, img[(size_t)r * WW + idx], Cs);
  inp[gid] = v;
}

// 8-block x 4-wave wavefront-pipelined scan, 1 row/thread, row-major I/O.
// Handoff protocol = R6's proven flag + acts-readback (fastest of R6-R8),
// with two refinements:
//  * producer release DEFERRED one epoch (to the top of the next epoch,
//    after the barrier): the release's vmcnt(0) drain covers stores that
//    already aged a full barrier -> off the critical path.
//  * 1 epoch of startup slack per block (wait for upstream flag[1] before
//    the loop): steady-state polls then hit on the first try instead of
//    spinning just-in-time against the producer's epoch boundary.
// Ring semantics (verified R2-R5): ring[e&1][w][i] = wave w's h AFTER column
// c0+i-1; slot 0 = h entering the chunk, slot i+1 = h after column i.
// inp/acts are the same buffer; loads touch chunk ch+1, stores chunk ch
// (disjoint 128B line ranges, same rows) except the final-chunk clamped
// reload whose result is never consumed -> restrict is operationally safe.
__global__ __launch_bounds__(NT) void scan_kernel(
    const float* __restrict__ w_state, const float* __restrict__ inp,
    float* __restrict__ acts, unsigned* __restrict__ flags) {
  const int t = threadIdx.x;
  const int wv = t >> 6;
  const int lane = t & 63;
  const int blk = blockIdx.x;
  const int r = blk * NT + t;                // global row (1 per thread)

  const float S = 2.88539008177792681472f;
  const float k0s = w_state[0] * S;
  const float k1s = w_state[1] * S;

  __shared__ float ring[2][NW][KCH];

  float h = 0.0f;
  const float* inrow = inp + (size_t)r * WSKP;
  float* myrow = acts + (size_t)r * WSKP;

  // Prime pf with chunk 0 (8 contiguous quads per lane).
  float4 pf[KCH / 4];
  #pragma unroll
  for (int q = 0; q < KCH / 4; ++q)
    pf[q] = *(const float4*)(inrow + 4 * q);

  const unsigned* upflag = flags + (blk - 1) * NCH;
  unsigned* myflag = flags + blk * NCH;
  const float* uprow = acts + ((size_t)(blk * NT) - 1) * WSKP;  // producer's last row

  // Startup slack + chunk-0 boundary prefetch (wave 0, blk>0 only).
  // bvec lane i (i<32) = neighbor-row h AFTER column c0+i-1.
  float bvec = 0.0f;
  if (wv == 0 && blk > 0) {
    while (__hip_atomic_load(upflag + 1, __ATOMIC_ACQUIRE,
                             __HIP_MEMORY_SCOPE_AGENT) != 2u)
      __builtin_amdgcn_s_sleep(2);
    int cl = lane - 1;
    if (lane < KCH && cl >= 0) bvec = uprow[cl];
  }

  for (int e = 0; e < NCH + NW - 1; ++e) {
    // Deferred release: flag for the chunk wave 3 finished LAST epoch.
    // Its stores aged through a full barrier -> the release's vmcnt(0)
    // drain is ~free here.
    if (wv == NW - 1 && blk + 1 < BLKS && lane == 63) {
      int chp = e - NW;                      // = (e-1) - (NW-1)
      if (chp >= 0)
        __hip_atomic_store(myflag + chp, (unsigned)(chp + 1),
                           __ATOMIC_RELEASE, __HIP_MEMORY_SCOPE_AGENT);
    }

    const int ch = e - wv;
    if (0 <= ch && ch < NCH) {
      const int c0 = ch * KCH;

      float bv;
      if (wv == 0) {
        bv = bvec;                           // prefetched (blk 0: stays 0)
      } else {
        bv = ring[(e & 1) ^ 1][wv - 1][lane & (KCH - 1)];
      }

      const float h0 = h;                    // ring slot 0 value
      float hbuf[KCH];
      const float* nx = inrow + (ch + 1 < NCH ? (ch + 1) : ch) * KCH;

      // Column loop: ZERO memory ops except 8 interleaved quad reloads
      // (issued right after their pf quad is fully consumed; ~28 columns
      // + a barrier of latency cover before next-epoch use).
      #pragma unroll
      for (int cc = 0; cc < KCH; ++cc) {
        float cur = PFE(cc);
        if ((cc & 3) == 3)
          pf[cc >> 2] = *(const float4*)(nx + (cc & ~3));

        float pv = __builtin_bit_cast(float,
            __builtin_amdgcn_readlane(__builtin_bit_cast(int, bv), cc));
        float prev = wave_shr1(h, pv);       // prev[l]=h[l-1], prev[0]=pv

        h = tanh_pre(fmaf(k0s, prev, fmaf(k1s, h, cur)));
        hbuf[cc] = h;
      }

      // Wave 0: poll + gather NEXT chunk's boundary BEFORE issuing our
      // stores (keeps the gather loads older than the stores -> the
      // next-epoch wait on bvec doesn't drain this epoch's stores).
      if (wv == 0 && blk > 0 && ch + 1 < NCH) {
        const unsigned want = (unsigned)(ch + 2);
        while (__hip_atomic_load(upflag + ch + 1, __ATOMIC_ACQUIRE,
                                 __HIP_MEMORY_SCOPE_AGENT) != want)
          __builtin_amdgcn_s_sleep(1);
        bvec = 0.0f;
        if (lane < KCH) bvec = uprow[(ch + 1) * KCH + lane - 1];
      }

      // Batched output: 8 contiguous dwordx4 stores per lane.
      #pragma unroll
      for (int q = 0; q < KCH / 4; ++q) {
        float4 s;
        s.x = hbuf[4 * q + 0]; s.y = hbuf[4 * q + 1];
        s.z = hbuf[4 * q + 2]; s.w = hbuf[4 * q + 3];
        *(float4*)(myrow + c0 + 4 * q) = s;
      }

      // Batched ring write (lane 63 of waves 0..2): [h0, hbuf[0..30]].
      if (lane == 63 && wv != NW - 1) {
        float* rp = &ring[e & 1][wv][0];
        rp[0] = h0;
        #pragma unroll
        for (int i = 1; i < KCH; ++i) rp[i] = hbuf[i - 1];
      }
    }
    // LDS-only barrier: rotates the ring double-buffer WITHOUT draining
    // vmcnt, so reload quads + bvec gather survive the epoch boundary.
    asm volatile("s_waitcnt lgkmcnt(0)\n\ts_barrier" ::: "memory");
  }

  // Final chunk's flag (its in-loop release slot would be epoch NCH+3).
  if (wv == NW - 1 && blk + 1 < BLKS && lane == 63)
    __hip_atomic_store(myflag + (NCH - 1), (unsigned)NCH,
                       __ATOMIC_RELEASE, __HIP_MEMORY_SCOPE_AGENT);
}

// Unskew + FC with row-major acts: flat[i][k] = acts_rm[i>>1][(i>>1) +
// (i&1)*1024 + k] -- CONTIGUOUS in k. One wave per flat row, fc_w staged
// in LDS (lane-consecutive reads, conflict-free), coalesced 256B row loads.
#define FCT 256
__global__ __launch_bounds__(FCT) void fc_kernel(
    const float* __restrict__ acts, const float* __restrict__ fc_w,
    const float* __restrict__ fc_b, float* __restrict__ out) {
  __shared__ float fcw[FC_OUT * FC_IN];      // 40 KB
  const int tid = threadIdx.x;
  for (int i = tid; i < FC_OUT * FC_IN; i += FCT) fcw[i] = fc_w[i];
  __syncthreads();

  const int wv = tid >> 6;
  const int lane = tid & 63;
  const int i = blockIdx.x * 4 + wv;         // flat row
  const int r = i >> 1;
  const float* arow = acts + (size_t)r * WSKP + r + ((i & 1) << 10);

  float acc[FC_OUT];
  #pragma unroll
  for (int j = 0; j < FC_OUT; ++j) acc[j] = 0.0f;

  #pragma unroll 4
  for (int k = lane; k < FC_IN; k += 64) {
    float v = arow[k];
    #pragma unroll
    for (int j = 0; j < FC_OUT; ++j)
      acc[j] = fmaf(v, fcw[j * FC_IN + k], acc[j]);
  }

  #pragma unroll
  for (int j = 0; j < FC_OUT; ++j) {
    #pragma unroll
    for (int off = 32; off > 0; off >>= 1)
      acc[j] += __shfl_down(acc[j], off);
  }
  if (lane == 0) {
    #pragma unroll
    for (int j = 0; j < FC_OUT; ++j)
      out[i * FC_OUT + j] = acc[j] + fc_b[j];
  }
}

extern "C" void kernel_launch(void* const* d_in, const int* in_sizes, int n_in,
                              void* d_out, int out_size, void* d_ws, size_t ws_size,
                              hipStream_t stream) {
  const float* x       = (const float*)d_in[0];
  const float* w_in    = (const float*)d_in[1];
  const float* b_in    = (const float*)d_in[2];
  const float* w_state = (const float*)d_in[3];
  const float* b_state = (const float*)d_in[4];
  const float* fc_w    = (const float*)d_in[5];
  const float* fc_b    = (const float*)d_in[6];
  float* out = (float*)d_out;
  float* buf = (float*)d_ws;   // HH*WSKP*4 = 32 MiB row-major: inp -> acts in-place

  // Flags live in d_out (4 KB of its 160 KB): scan writes tags 1..128 there;
  // fc_kernel later overwrites EVERY d_out element with real outputs, so
  // validation is unaffected. Harness poison (0xAA..) / memset(0) / fc float
  // bit patterns never equal a tag, so flags are correctly reset per launch.
  // (Must be d_out, not d_ws: d_ws is NOT re-poisoned between launches.)
  unsigned* flags = (unsigned*)d_out;

  skew_kernel<<<(HH * WSKP) / 256, 256, 0, stream>>>(x, w_in, b_in, b_state, buf);
  scan_kernel<<<BLKS, NT, 0, stream>>>(w_state, buf, buf, flags);
  fc_kernel<<<(HH * WW / FC_IN) / 4, FCT, 0, stream>>>(buf, fc_w, fc_b, out);
}